// Round 8
// baseline (269.862 us; speedup 1.0000x reference)
//
#include <hip/hip_runtime.h>
#include <math.h>

namespace {
constexpr int DETN = 816;
constexpr int NVIEW = 720;
constexpr int NB = 8;
constexpr int IMGN = 512;
constexpr float PIXSZ = 0.5f;
constexpr float SID = 750.0f;
constexpr float SDD = 1250.0f;
constexpr float DBETA = 6.28318530717958647692f / 720.0f;

constexpr int XPAD = 1632;       // 407 left zeros + 816 data + 409 right zeros
constexpr int T = 16;            // outputs per thread
constexpr int TPR = DETN / T;    // 51 threads per row
constexpr int ROWSTRIDE = 1736;  // > skew(1631)=1732
constexpr int NBB = 4;           // batches per filter block

constexpr int NSPLIT = 2;
constexpr int VH = NVIEW / NSPLIT;   // 360 views per half
constexpr int VP = VH / 2;           // 180 view-pairs

typedef _Float16 h2 __attribute__((ext_vector_type(2)));
typedef float f2 __attribute__((ext_vector_type(2)));

__device__ __forceinline__ int skew(int i) { return i + (i >> 4); }
__device__ __forceinline__ f2 fma2(f2 a, f2 b, f2 c) {
  return __builtin_elementwise_fma(a, b, c);
}
__device__ __forceinline__ h2 pack_h2(float a, float b) {
  return __builtin_bit_cast(h2, __builtin_amdgcn_cvt_pkrtz(a, b));
}

// One block per (view, batch-half): 4 rows. Ramp filter (odd-d taps + center),
// scale by cosw, write PAIRED fp16: word[v][w][b] = (y[w][b], y[w+1][b]).
// Conv in packed-f32: window pairs p[j]=(win[j],win[j+8]), acc2[k]=(y[k],y[k+8]).
__global__ __launch_bounds__(256) void filt_kernel(
    const float* __restrict__ x, const float* __restrict__ filt,
    h2* __restrict__ sino2)
{
  __shared__ float xs[NBB * ROWSTRIDE];   // 27.8 KB; reused as ys after conv
  const int tid = threadIdx.x;
  const int v = blockIdx.x >> 1;
  const int bhalf = blockIdx.x & 1;

  // stage 4 rows (batches bhalf*4 ..+3) of view v, zero-padded, skewed
  for (int p = tid; p < NBB * XPAD; p += 256) {
    int b = p / XPAD;
    int q = p - b * XPAD;
    int src = q - 407;
    float val = 0.0f;
    if (src >= 0 && src < DETN)
      val = x[((bhalf * NBB + b) * NVIEW + v) * DETN + src];
    xs[b * ROWSTRIDE + skew(q)] = val;
  }
  __syncthreads();

  const bool active = tid < NBB * TPR;   // 204 compute threads
  const int b = tid / TPR;
  const int t = tid - b * TPR;
  const int w0 = t * T;
  f2 acc2[8];

  if (active) {
    const float* __restrict__ xrow = &xs[b * ROWSTRIDE];
    f2 p[8];   // p[j] = (win[j], win[j+8]); win[i] = xs_padded[w0+2s+i]
#pragma unroll
    for (int k = 0; k < 8; ++k) {
      p[k].x = xrow[skew(w0 + k)];
      p[k].y = xrow[skew(w0 + k + 8)];
      acc2[k] = (f2){0.0f, 0.0f};
    }

    // 408 even-index taps (odd d), stepping 2; unroll 8 (2s mod 16 period 8)
    for (int s8 = 0; s8 < 51; ++s8) {
#pragma unroll
      for (int u = 0; u < 8; ++u) {
        const int s = s8 * 8 + u;
        const float fv = filt[2 * s];          // wave-uniform -> s_load
        const f2 fv2 = {fv, fv};
#pragma unroll
        for (int k = 0; k < 8; ++k) {
          const int idx = (2 * u + k) & 15;    // compile-time after unroll
          const f2 v2 = (idx < 8)
              ? p[idx]
              : __builtin_shufflevector(p[idx - 8], p[idx - 8], 1, 0);
          acc2[k] = fma2(v2, fv2, acc2[k]);
        }
        const float nv0 = xrow[skew(w0 + 2 * s + 16)];
        const float nv1 = xrow[skew(w0 + 2 * s + 17)];
        if (2 * u < 8) p[2 * u].x = nv0; else p[2 * u - 8].y = nv0;
        if (2 * u + 1 < 8) p[2 * u + 1].x = nv1; else p[2 * u - 7].y = nv1;
      }
    }
    // center tap
    const float fc = filt[407];
    const f2 fc2 = {fc, fc};
#pragma unroll
    for (int k = 0; k < 8; ++k) {
      f2 v2;
      v2.x = xrow[skew(w0 + k + 407)];
      v2.y = xrow[skew(w0 + k + 415)];
      acc2[k] = fma2(v2, fc2, acc2[k]);
    }
    // fold cos-weight
#pragma unroll
    for (int k = 0; k < 8; ++k) {
      const float udx = (float)(w0 + k) - 407.5f;
      const float udy = (float)(w0 + k + 8) - 407.5f;
      acc2[k].x *= SID / sqrtf(SID * SID + udx * udx);
      acc2[k].y *= SID / sqrtf(SID * SID + udy * udy);
    }
  }
  __syncthreads();          // all xs reads done -> reuse as ys

  float* ys = xs;           // [NBB][DETN+1]
  if (active) {
#pragma unroll
    for (int k = 0; k < 8; ++k) {
      ys[b * (DETN + 1) + w0 + k] = acc2[k].x;
      ys[b * (DETN + 1) + w0 + k + 8] = acc2[k].y;
    }
    if (t == 0) ys[b * (DETN + 1) + DETN] = 0.0f;   // pad
  }
  __syncthreads();

  // pair-pack write: word idx = w*8 + bhalf*4 + bb  (16B contiguous per det)
  h2* dst = sino2 + (size_t)v * DETN * NB + bhalf * NBB;
  for (int idx = tid; idx < DETN * NBB; idx += 256) {
    const int w = idx >> 2;
    const int bb = idx & 3;
    h2 hp;
    hp[0] = (_Float16)ys[bb * (DETN + 1) + w];
    hp[1] = (_Float16)ys[bb * (DETN + 1) + w + 1];
    dst[w * 8 + bb] = hp;
  }
}

__device__ __forceinline__ float dot2acc(h2 w, unsigned int q, float acc) {
  return __builtin_amdgcn_fdot2(w, __builtin_bit_cast(h2, q), acc, false);
}

// 32x32-pixel blocks (1024 threads) -> 2 blocks/CU, small per-CU view window
// for L1 residency of the gather stream.
__global__ __launch_bounds__(1024, 2) void bp_kernel(
    const h2* __restrict__ sino2, float* __restrict__ out)
{
  // per view-pair tables: (cosA,cosB), (sinA,sinB), SDD-scaled versions
  __shared__ f2 cbp_t[VP], sbp_t[VP], csp_t[VP], ssp_t[VP];
  const int tid = threadIdx.x;
  const int v0 = blockIdx.z * VH;
  for (int it = tid; it < VP; it += 1024) {
    float sA, cA, sB, cB;
    sincosf((float)(v0 + 2 * it) * DBETA, &sA, &cA);
    sincosf((float)(v0 + 2 * it + 1) * DBETA, &sB, &cB);
    cbp_t[it] = (f2){cA, cB};
    sbp_t[it] = (f2){sA, sB};
    csp_t[it] = (f2){SDD * cA, SDD * cB};
    ssp_t[it] = (f2){SDD * sA, SDD * sB};
  }
  __syncthreads();

  // wave = 8x8 pixel patch; block = 32x32 tile (4x4 waves)
  const int lane = tid & 63;
  const int wv = tid >> 6;
  const int px = ((wv & 3) << 3) | (lane & 7);
  const int py = ((wv >> 2) << 3) | (lane >> 3);
  const int j = (blockIdx.x << 5) + px;
  const int i = (blockIdx.y << 5) + py;
  const float X = ((float)j - 255.5f) * PIXSZ;
  const float Y = -(((float)i - 255.5f) * PIXSZ);
  const f2 X2 = {X, X};
  const f2 Y2 = {Y, Y};
  const f2 nY2 = {-Y, -Y};
  const f2 SID2 = {SID, SID};
  const f2 C4075 = {407.5f, 407.5f};

  float acc[NB];
#pragma unroll
  for (int b = 0; b < NB; ++b) acc[b] = 0.0f;

  const char* pv = (const char*)sino2 + (size_t)v0 * DETN * NB * 4;
  constexpr int VSTRIDE = DETN * NB * 4;   // bytes per view (paired fp16)

  for (int it = 0; it < VP; ++it) {
    const f2 cbp = cbp_t[it];
    const f2 sbp = sbp_t[it];
    const f2 csp = csp_t[it];
    const f2 ssp = ssp_t[it];

    const f2 num = fma2(Y2, ssp, X2 * csp);          // SDD * xr  (A,B)
    const f2 L = fma2(nY2, cbp, fma2(X2, sbp, SID2));
    const float rA = __builtin_amdgcn_rcpf(L.x);
    const float rB = __builtin_amdgcn_rcpf(L.y);
    const f2 rL = {rA, rB};
    const f2 tt = fma2(num, rL, C4075);              // t in [97.5, 717.5]
    const f2 m = SID2 * rL;
    const f2 w = m * m;
    const float i0fA = floorf(tt.x);
    const float i0fB = floorf(tt.y);
    const int i0A = (int)i0fA;
    const int i0B = (int)i0fB;
    const f2 frac = tt - (f2){i0fA, i0fB};
    const f2 a1 = w * frac;
    const f2 a0 = w - a1;
    const h2 wpA = pack_h2(a0.x, a1.x);
    const h2 wpB = pack_h2(a0.y, a1.y);

    // 32B per view: 8 pair-words (b0..b7) at det i0 -> 2x dwordx4
    const uint4* pA = (const uint4*)(pv + (i0A << 5));
    const uint4* pB = (const uint4*)(pv + VSTRIDE + (i0B << 5));
    const uint4 qA0 = pA[0];   // pairs b0-3
    const uint4 qA1 = pA[1];   // pairs b4-7
    const uint4 qB0 = pB[0];
    const uint4 qB1 = pB[1];

    acc[0] = dot2acc(wpA, qA0.x, acc[0]);
    acc[1] = dot2acc(wpA, qA0.y, acc[1]);
    acc[2] = dot2acc(wpA, qA0.z, acc[2]);
    acc[3] = dot2acc(wpA, qA0.w, acc[3]);
    acc[4] = dot2acc(wpA, qA1.x, acc[4]);
    acc[5] = dot2acc(wpA, qA1.y, acc[5]);
    acc[6] = dot2acc(wpA, qA1.z, acc[6]);
    acc[7] = dot2acc(wpA, qA1.w, acc[7]);

    acc[0] = dot2acc(wpB, qB0.x, acc[0]);
    acc[1] = dot2acc(wpB, qB0.y, acc[1]);
    acc[2] = dot2acc(wpB, qB0.z, acc[2]);
    acc[3] = dot2acc(wpB, qB0.w, acc[3]);
    acc[4] = dot2acc(wpB, qB1.x, acc[4]);
    acc[5] = dot2acc(wpB, qB1.y, acc[5]);
    acc[6] = dot2acc(wpB, qB1.z, acc[6]);
    acc[7] = dot2acc(wpB, qB1.w, acc[7]);

    pv += 2 * VSTRIDE;
  }

#pragma unroll
  for (int b = 0; b < NB; ++b)
    atomicAdd(&out[(b * IMGN + i) * IMGN + j], acc[b] * DBETA);
}

} // namespace

extern "C" void kernel_launch(void* const* d_in, const int* in_sizes, int n_in,
                              void* d_out, int out_size, void* d_ws, size_t ws_size,
                              hipStream_t stream) {
  const float* x = (const float*)d_in[0];
  const float* filt = (const float*)d_in[1];
  float* out = (float*)d_out;
  h2* sino2 = (h2*)d_ws;   // 720*816*8 paired-fp16 words = 18.8 MB

  (void)hipMemsetAsync(out, 0, (size_t)out_size * sizeof(float), stream);
  filt_kernel<<<NVIEW * 2, 256, 0, stream>>>(x, filt, sino2);
  bp_kernel<<<dim3(IMGN / 32, IMGN / 32, NSPLIT), 1024, 0, stream>>>(sino2, out);
}

// Round 9
// 254.174 us; speedup vs baseline: 1.0617x; 1.0617x over previous
//
#include <hip/hip_runtime.h>
#include <math.h>

namespace {
constexpr int DETN = 816;
constexpr int NVIEW = 720;
constexpr int NB = 8;
constexpr int IMGN = 512;
constexpr float PIXSZ = 0.5f;
constexpr float SID = 750.0f;
constexpr float SDD = 1250.0f;
constexpr float DBETA = 6.28318530717958647692f / 720.0f;

constexpr int XPAD = 1632;       // 407 left zeros + 816 data + 409 right zeros
constexpr int T = 16;            // outputs per thread
constexpr int TPR = DETN / T;    // 51 threads per row
constexpr int ROWSTRIDE = 1840;  // > F(1631)=1833, even
constexpr int NBB = 4;           // batches per filter block

constexpr int NSPLIT = 2;
constexpr int VH = NVIEW / NSPLIT;   // 360 views per half
constexpr int VP = VH / 2;           // 180 view-pairs
constexpr int VQ = VH / 4;           // 90 view-quads

typedef _Float16 h2 __attribute__((ext_vector_type(2)));
typedef float f2 __attribute__((ext_vector_type(2)));

// pair-skewed float index: F(i) = i + 2*(i>>4); keeps (2p,2p+1) adjacent and
// 8B-aligned, pads 2 floats every 16 -> refill bank stride 18 (4-way, 1.58x)
__device__ __forceinline__ int F(int i) { return i + 2 * (i >> 4); }
__device__ __forceinline__ int pairF(int pp) { return 2 * pp + 2 * (pp >> 3); }

__device__ __forceinline__ f2 fma2(f2 a, f2 b, f2 c) {
  return __builtin_elementwise_fma(a, b, c);
}
__device__ __forceinline__ h2 pack_h2(float a, float b) {
  return __builtin_bit_cast(h2, __builtin_amdgcn_cvt_pkrtz(a, b));
}

// One block per (view, batch-half): 4 rows. Ramp filter (odd-d taps + center),
// scale by cosw, write PAIRED fp16: word[v][w][b] = (y[w][b], y[w+1][b]).
// Window ring: q[(s+k)&7] = (x[w0+2(s+k)], x[w0+2(s+k)+1]); one b64 refill/step.
__global__ __launch_bounds__(256) void filt_kernel(
    const float* __restrict__ x, const float* __restrict__ filt,
    h2* __restrict__ sino2)
{
  __shared__ float xs[NBB * ROWSTRIDE];   // 29.4 KB; reused as ys after conv
  const int tid = threadIdx.x;
  const int v = blockIdx.x >> 1;
  const int bhalf = blockIdx.x & 1;

  // stage 4 rows (batches bhalf*4 ..+3) of view v, zero-padded, pair-skewed
  for (int p = tid; p < NBB * XPAD; p += 256) {
    int b = p / XPAD;
    int qq = p - b * XPAD;
    int src = qq - 407;
    float val = 0.0f;
    if (src >= 0 && src < DETN)
      val = x[((bhalf * NBB + b) * NVIEW + v) * DETN + src];
    xs[b * ROWSTRIDE + F(qq)] = val;
  }
  __syncthreads();

  const bool active = tid < NBB * TPR;   // 204 compute threads
  const int b = tid / TPR;
  const int t = tid - b * TPR;
  const int w0 = t * T;
  f2 acc2[8];   // acc2[k] = (y[w0+2k], y[w0+2k+1])

  if (active) {
    const float* __restrict__ xrow = &xs[b * ROWSTRIDE];
    const int P0 = 8 * t;     // base pair position
    f2 q[8];                  // ring: slot (s+k)&7 holds pair pos P0+s+k
#pragma unroll
    for (int k = 0; k < 8; ++k) {
      q[k] = *(const f2*)&xrow[pairF(P0 + k)];
      acc2[k] = (f2){0.0f, 0.0f};
    }

    // 408 even-index taps (odd d), step 2 floats = 1 pair; unroll 8
    for (int s8 = 0; s8 < 51; ++s8) {
#pragma unroll
      for (int u = 0; u < 8; ++u) {
        const int s = s8 * 8 + u;
        const float fv = filt[2 * s];          // wave-uniform -> s_load
        const f2 fv2 = {fv, fv};
#pragma unroll
        for (int k = 0; k < 8; ++k)
          acc2[k] = fma2(q[(u + k) & 7], fv2, acc2[k]);
        q[u & 7] = *(const f2*)&xrow[pairF(P0 + s + 8)];   // pos s+8
      }
    }
    // center tap (odd float offset 407 -> scalar reads)
    const float fc = filt[407];
#pragma unroll
    for (int k = 0; k < 8; ++k) {
      acc2[k].x = fmaf(xrow[F(w0 + 2 * k + 407)], fc, acc2[k].x);
      acc2[k].y = fmaf(xrow[F(w0 + 2 * k + 408)], fc, acc2[k].y);
    }
    // fold cos-weight
#pragma unroll
    for (int k = 0; k < 8; ++k) {
      const float udx = (float)(w0 + 2 * k) - 407.5f;
      const float udy = (float)(w0 + 2 * k + 1) - 407.5f;
      acc2[k].x *= SID / sqrtf(SID * SID + udx * udx);
      acc2[k].y *= SID / sqrtf(SID * SID + udy * udy);
    }
  }
  __syncthreads();          // all xs reads done -> reuse as ys

  float* ys = xs;           // [NBB][DETN+1]
  if (active) {
#pragma unroll
    for (int k = 0; k < 8; ++k) {
      ys[b * (DETN + 1) + w0 + 2 * k] = acc2[k].x;
      ys[b * (DETN + 1) + w0 + 2 * k + 1] = acc2[k].y;
    }
    if (t == 0) ys[b * (DETN + 1) + DETN] = 0.0f;   // pad
  }
  __syncthreads();

  // pair-pack write: word idx = w*8 + bhalf*4 + bb  (16B contiguous per det)
  h2* dst = sino2 + (size_t)v * DETN * NB + bhalf * NBB;
  for (int idx = tid; idx < DETN * NBB; idx += 256) {
    const int w = idx >> 2;
    const int bb = idx & 3;
    h2 hp;
    hp[0] = (_Float16)ys[bb * (DETN + 1) + w];
    hp[1] = (_Float16)ys[bb * (DETN + 1) + w + 1];
    dst[w * 8 + bb] = hp;
  }
}

__device__ __forceinline__ float dot2acc(h2 w, unsigned int q, float acc) {
  return __builtin_amdgcn_fdot2(w, __builtin_bit_cast(h2, q), acc, false);
}

// 16x16-pixel blocks; 4-view unroll for MLP (8 independent dwordx4 in flight).
__global__ __launch_bounds__(256, 6) void bp_kernel(
    const h2* __restrict__ sino2, float* __restrict__ out)
{
  // per view-pair tables: (cos,cos), (sin,sin), SDD-scaled versions
  __shared__ f2 cbp_t[VP], sbp_t[VP], csp_t[VP], ssp_t[VP];
  const int tid = threadIdx.x;
  const int v0 = blockIdx.z * VH;
  for (int it = tid; it < VP; it += 256) {
    float sA, cA, sB, cB;
    sincosf((float)(v0 + 2 * it) * DBETA, &sA, &cA);
    sincosf((float)(v0 + 2 * it + 1) * DBETA, &sB, &cB);
    cbp_t[it] = (f2){cA, cB};
    sbp_t[it] = (f2){sA, sB};
    csp_t[it] = (f2){SDD * cA, SDD * cB};
    ssp_t[it] = (f2){SDD * sA, SDD * sB};
  }
  __syncthreads();

  // wave = 8x8 pixel patch; block = 16x16 tile
  const int lane = tid & 63;
  const int wv = tid >> 6;
  const int px = ((wv & 1) << 3) | (lane & 7);
  const int py = ((wv >> 1) << 3) | (lane >> 3);
  const int j = (blockIdx.x << 4) + px;
  const int i = (blockIdx.y << 4) + py;
  const float X = ((float)j - 255.5f) * PIXSZ;
  const float Y = -(((float)i - 255.5f) * PIXSZ);
  const f2 X2 = {X, X};
  const f2 Y2 = {Y, Y};
  const f2 nY2 = {-Y, -Y};
  const f2 SID2 = {SID, SID};
  const f2 C4075 = {407.5f, 407.5f};

  float acc[NB];
#pragma unroll
  for (int b = 0; b < NB; ++b) acc[b] = 0.0f;

  const char* pv = (const char*)sino2 + (size_t)v0 * DETN * NB * 4;
  constexpr int VSTRIDE = DETN * NB * 4;   // bytes per view (paired fp16)

  for (int qd = 0; qd < VQ; ++qd) {
    // ---- geometry for views 4qd..4qd+3 as two f2 pairs ----
    const f2 cb0 = cbp_t[2 * qd],     cb1 = cbp_t[2 * qd + 1];
    const f2 sb0 = sbp_t[2 * qd],     sb1 = sbp_t[2 * qd + 1];
    const f2 cs0 = csp_t[2 * qd],     cs1 = csp_t[2 * qd + 1];
    const f2 ss0 = ssp_t[2 * qd],     ss1 = ssp_t[2 * qd + 1];

    const f2 num0 = fma2(Y2, ss0, X2 * cs0);
    const f2 num1 = fma2(Y2, ss1, X2 * cs1);
    const f2 L0 = fma2(nY2, cb0, fma2(X2, sb0, SID2));
    const f2 L1 = fma2(nY2, cb1, fma2(X2, sb1, SID2));
    const f2 rL0 = {__builtin_amdgcn_rcpf(L0.x), __builtin_amdgcn_rcpf(L0.y)};
    const f2 rL1 = {__builtin_amdgcn_rcpf(L1.x), __builtin_amdgcn_rcpf(L1.y)};
    const f2 tt0 = fma2(num0, rL0, C4075);   // t in [97.5, 717.5] -> no clamp
    const f2 tt1 = fma2(num1, rL1, C4075);
    const f2 m0 = SID2 * rL0, m1 = SID2 * rL1;
    const f2 w0 = m0 * m0, w1 = m1 * m1;
    const float iA = floorf(tt0.x), iB = floorf(tt0.y);
    const float iC = floorf(tt1.x), iD = floorf(tt1.y);
    const int i0A = (int)iA, i0B = (int)iB, i0C = (int)iC, i0D = (int)iD;
    const f2 fr0 = tt0 - (f2){iA, iB};
    const f2 fr1 = tt1 - (f2){iC, iD};
    const f2 a1p0 = w0 * fr0, a1p1 = w1 * fr1;
    const f2 a0p0 = w0 - a1p0, a0p1 = w1 - a1p1;
    const h2 wpA = pack_h2(a0p0.x, a1p0.x);
    const h2 wpB = pack_h2(a0p0.y, a1p0.y);
    const h2 wpC = pack_h2(a0p1.x, a1p1.x);
    const h2 wpD = pack_h2(a0p1.y, a1p1.y);

    // ---- 8 independent dwordx4 gathers ----
    const uint4* pA = (const uint4*)(pv + (i0A << 5));
    const uint4* pB = (const uint4*)(pv + VSTRIDE + (i0B << 5));
    const uint4* pC = (const uint4*)(pv + 2 * VSTRIDE + (i0C << 5));
    const uint4* pD = (const uint4*)(pv + 3 * VSTRIDE + (i0D << 5));
    const uint4 qA0 = pA[0], qA1 = pA[1];
    const uint4 qB0 = pB[0], qB1 = pB[1];
    const uint4 qC0 = pC[0], qC1 = pC[1];
    const uint4 qD0 = pD[0], qD1 = pD[1];

    acc[0] = dot2acc(wpA, qA0.x, acc[0]);
    acc[1] = dot2acc(wpA, qA0.y, acc[1]);
    acc[2] = dot2acc(wpA, qA0.z, acc[2]);
    acc[3] = dot2acc(wpA, qA0.w, acc[3]);
    acc[4] = dot2acc(wpA, qA1.x, acc[4]);
    acc[5] = dot2acc(wpA, qA1.y, acc[5]);
    acc[6] = dot2acc(wpA, qA1.z, acc[6]);
    acc[7] = dot2acc(wpA, qA1.w, acc[7]);

    acc[0] = dot2acc(wpB, qB0.x, acc[0]);
    acc[1] = dot2acc(wpB, qB0.y, acc[1]);
    acc[2] = dot2acc(wpB, qB0.z, acc[2]);
    acc[3] = dot2acc(wpB, qB0.w, acc[3]);
    acc[4] = dot2acc(wpB, qB1.x, acc[4]);
    acc[5] = dot2acc(wpB, qB1.y, acc[5]);
    acc[6] = dot2acc(wpB, qB1.z, acc[6]);
    acc[7] = dot2acc(wpB, qB1.w, acc[7]);

    acc[0] = dot2acc(wpC, qC0.x, acc[0]);
    acc[1] = dot2acc(wpC, qC0.y, acc[1]);
    acc[2] = dot2acc(wpC, qC0.z, acc[2]);
    acc[3] = dot2acc(wpC, qC0.w, acc[3]);
    acc[4] = dot2acc(wpC, qC1.x, acc[4]);
    acc[5] = dot2acc(wpC, qC1.y, acc[5]);
    acc[6] = dot2acc(wpC, qC1.z, acc[6]);
    acc[7] = dot2acc(wpC, qC1.w, acc[7]);

    acc[0] = dot2acc(wpD, qD0.x, acc[0]);
    acc[1] = dot2acc(wpD, qD0.y, acc[1]);
    acc[2] = dot2acc(wpD, qD0.z, acc[2]);
    acc[3] = dot2acc(wpD, qD0.w, acc[3]);
    acc[4] = dot2acc(wpD, qD1.x, acc[4]);
    acc[5] = dot2acc(wpD, qD1.y, acc[5]);
    acc[6] = dot2acc(wpD, qD1.z, acc[6]);
    acc[7] = dot2acc(wpD, qD1.w, acc[7]);

    pv += 4 * VSTRIDE;
  }

#pragma unroll
  for (int b = 0; b < NB; ++b)
    atomicAdd(&out[(b * IMGN + i) * IMGN + j], acc[b] * DBETA);
}

} // namespace

extern "C" void kernel_launch(void* const* d_in, const int* in_sizes, int n_in,
                              void* d_out, int out_size, void* d_ws, size_t ws_size,
                              hipStream_t stream) {
  const float* x = (const float*)d_in[0];
  const float* filt = (const float*)d_in[1];
  float* out = (float*)d_out;
  h2* sino2 = (h2*)d_ws;   // 720*816*8 paired-fp16 words = 18.8 MB

  (void)hipMemsetAsync(out, 0, (size_t)out_size * sizeof(float), stream);
  filt_kernel<<<NVIEW * 2, 256, 0, stream>>>(x, filt, sino2);
  bp_kernel<<<dim3(IMGN / 16, IMGN / 16, NSPLIT), 256, 0, stream>>>(sino2, out);
}

// Round 10
// 250.200 us; speedup vs baseline: 1.0786x; 1.0159x over previous
//
#include <hip/hip_runtime.h>
#include <math.h>

namespace {
constexpr int DETN = 816;
constexpr int NVIEW = 720;
constexpr int NB = 8;
constexpr int IMGN = 512;
constexpr float PIXSZ = 0.5f;
constexpr float SID = 750.0f;
constexpr float SDD = 1250.0f;
constexpr float DBETA = 6.28318530717958647692f / 720.0f;

constexpr int XPAD2 = 1648;      // 407 left zeros + 816 data + 425 right zeros
constexpr int T = 16;            // outputs per thread
constexpr int TPR = DETN / T;    // 51 threads per row
constexpr int ROWSTRIDE = 1852;  // > F(1647)=1851, even
constexpr int NBB = 4;           // batches per filter block

constexpr int NSPLIT = 2;
constexpr int VH = NVIEW / NSPLIT;   // 360 views per half
constexpr int VP = VH / 2;           // 180 view-pairs
constexpr int VQ = VH / 4;           // 90 view-quads

typedef _Float16 h2 __attribute__((ext_vector_type(2)));
typedef float f2 __attribute__((ext_vector_type(2)));

// pair-skewed float index: F(i) = i + 2*(i>>4); keeps (2p,2p+1) adjacent and
// 8B-aligned, pads 2 floats every 16 -> refill bank stride 18 (4-way, 1.58x)
__device__ __forceinline__ int F(int i) { return i + 2 * (i >> 4); }
__device__ __forceinline__ int pairF(int pp) { return 2 * pp + 2 * (pp >> 3); }

__device__ __forceinline__ f2 fma2(f2 a, f2 b, f2 c) {
  return __builtin_elementwise_fma(a, b, c);
}
__device__ __forceinline__ h2 pack_h2(float a, float b) {
  return __builtin_bit_cast(h2, __builtin_amdgcn_cvt_pkrtz(a, b));
}

// One block per (view, batch-half): 4 rows. Ramp filter (odd-d taps + center),
// scale by cosw, write PAIRED fp16: word[v][w][b] = (y[w][b], y[w+1][b]).
// 16-deep register ring: slot (s+k)&15 holds pair P0+s+k; refill of pair
// P0+s+16 lands in the slot vacated at step s and is first used 9 steps
// later (~144 issue-cycles) -> LDS latency fully hidden by ILP.
__global__ __launch_bounds__(256) void filt_kernel(
    const float* __restrict__ x, const float* __restrict__ filt,
    h2* __restrict__ sino2)
{
  __shared__ float xs[NBB * ROWSTRIDE];   // 29.6 KB; reused as ys after conv
  const int tid = threadIdx.x;
  const int v = blockIdx.x >> 1;
  const int bhalf = blockIdx.x & 1;

  // stage 4 rows (batches bhalf*4 ..+3) of view v, zero-padded, pair-skewed
  for (int b = 0; b < NBB; ++b) {
    const float* __restrict__ src = &x[((bhalf * NBB + b) * NVIEW + v) * DETN];
    for (int qq = tid; qq < XPAD2; qq += 256) {
      const int s = qq - 407;
      float val = 0.0f;
      if (s >= 0 && s < DETN) val = src[s];
      xs[b * ROWSTRIDE + F(qq)] = val;
    }
  }
  __syncthreads();

  const bool active = tid < NBB * TPR;   // 204 compute threads
  const int b = tid / TPR;
  const int t = tid - b * TPR;
  const int w0 = t * T;
  f2 acc2[8];   // acc2[k] = (y[w0+2k], y[w0+2k+1])

  if (active) {
    const float* __restrict__ xrow = &xs[b * ROWSTRIDE];
    const int P0 = 8 * t;     // base pair position
    f2 q16[16];               // ring: slot (s+k)&15 holds pair pos P0+s+k
#pragma unroll
    for (int k = 0; k < 16; ++k)
      q16[k] = *(const f2*)&xrow[pairF(P0 + k)];
#pragma unroll
    for (int k = 0; k < 8; ++k) acc2[k] = (f2){0.0f, 0.0f};

    // 408 even-index taps (odd d): 25 double-groups of 16 + tail 8
    for (int g = 0; g < 26; ++g) {
#pragma unroll
      for (int u = 0; u < 8; ++u) {
        const int s = 16 * g + u;
        const float fv = filt[2 * s];          // wave-uniform -> s_load
        const f2 fv2 = {fv, fv};
#pragma unroll
        for (int k = 0; k < 8; ++k)
          acc2[k] = fma2(q16[(u + k) & 15], fv2, acc2[k]);
        q16[u] = *(const f2*)&xrow[pairF(P0 + s + 16)];
      }
      if (g == 25) break;      // steps 400..407 done
#pragma unroll
      for (int u = 0; u < 8; ++u) {
        const int s = 16 * g + 8 + u;
        const float fv = filt[2 * s];
        const f2 fv2 = {fv, fv};
#pragma unroll
        for (int k = 0; k < 8; ++k)
          acc2[k] = fma2(q16[(8 + u + k) & 15], fv2, acc2[k]);
        q16[8 + u] = *(const f2*)&xrow[pairF(P0 + s + 16)];
      }
    }
    // center tap (odd float offset 407 -> scalar reads)
    const float fc = filt[407];
#pragma unroll
    for (int k = 0; k < 8; ++k) {
      acc2[k].x = fmaf(xrow[F(w0 + 2 * k + 407)], fc, acc2[k].x);
      acc2[k].y = fmaf(xrow[F(w0 + 2 * k + 408)], fc, acc2[k].y);
    }
    // fold cos-weight
#pragma unroll
    for (int k = 0; k < 8; ++k) {
      const float udx = (float)(w0 + 2 * k) - 407.5f;
      const float udy = (float)(w0 + 2 * k + 1) - 407.5f;
      acc2[k].x *= SID / sqrtf(SID * SID + udx * udx);
      acc2[k].y *= SID / sqrtf(SID * SID + udy * udy);
    }
  }
  __syncthreads();          // all xs reads done -> reuse as ys

  float* ys = xs;           // [NBB][DETN+1]
  if (active) {
#pragma unroll
    for (int k = 0; k < 8; ++k) {
      ys[b * (DETN + 1) + w0 + 2 * k] = acc2[k].x;
      ys[b * (DETN + 1) + w0 + 2 * k + 1] = acc2[k].y;
    }
    if (t == 0) ys[b * (DETN + 1) + DETN] = 0.0f;   // pad
  }
  __syncthreads();

  // pair-pack write: word idx = w*8 + bhalf*4 + bb  (16B contiguous per det)
  h2* dst = sino2 + (size_t)v * DETN * NB + bhalf * NBB;
  for (int idx = tid; idx < DETN * NBB; idx += 256) {
    const int w = idx >> 2;
    const int bb = idx & 3;
    h2 hp;
    hp[0] = (_Float16)ys[bb * (DETN + 1) + w];
    hp[1] = (_Float16)ys[bb * (DETN + 1) + w + 1];
    dst[w * 8 + bb] = hp;
  }
}

__device__ __forceinline__ float dot2acc(h2 w, unsigned int q, float acc) {
  return __builtin_amdgcn_fdot2(w, __builtin_bit_cast(h2, q), acc, false);
}

// 16x16-pixel blocks; 4-view unroll for MLP (8 independent dwordx4 in flight).
__global__ __launch_bounds__(256, 6) void bp_kernel(
    const h2* __restrict__ sino2, float* __restrict__ out)
{
  // per view-pair tables: (cos,cos), (sin,sin), SDD-scaled versions
  __shared__ f2 cbp_t[VP], sbp_t[VP], csp_t[VP], ssp_t[VP];
  const int tid = threadIdx.x;
  const int v0 = blockIdx.z * VH;
  for (int it = tid; it < VP; it += 256) {
    float sA, cA, sB, cB;
    sincosf((float)(v0 + 2 * it) * DBETA, &sA, &cA);
    sincosf((float)(v0 + 2 * it + 1) * DBETA, &sB, &cB);
    cbp_t[it] = (f2){cA, cB};
    sbp_t[it] = (f2){sA, sB};
    csp_t[it] = (f2){SDD * cA, SDD * cB};
    ssp_t[it] = (f2){SDD * sA, SDD * sB};
  }
  __syncthreads();

  // wave = 8x8 pixel patch; block = 16x16 tile
  const int lane = tid & 63;
  const int wv = tid >> 6;
  const int px = ((wv & 1) << 3) | (lane & 7);
  const int py = ((wv >> 1) << 3) | (lane >> 3);
  const int j = (blockIdx.x << 4) + px;
  const int i = (blockIdx.y << 4) + py;
  const float X = ((float)j - 255.5f) * PIXSZ;
  const float Y = -(((float)i - 255.5f) * PIXSZ);
  const f2 X2 = {X, X};
  const f2 Y2 = {Y, Y};
  const f2 nY2 = {-Y, -Y};
  const f2 SID2 = {SID, SID};
  const f2 C4075 = {407.5f, 407.5f};

  float acc[NB];
#pragma unroll
  for (int b = 0; b < NB; ++b) acc[b] = 0.0f;

  const char* pv = (const char*)sino2 + (size_t)v0 * DETN * NB * 4;
  constexpr int VSTRIDE = DETN * NB * 4;   // bytes per view (paired fp16)

  for (int qd = 0; qd < VQ; ++qd) {
    // ---- geometry for views 4qd..4qd+3 as two f2 pairs ----
    const f2 cb0 = cbp_t[2 * qd],     cb1 = cbp_t[2 * qd + 1];
    const f2 sb0 = sbp_t[2 * qd],     sb1 = sbp_t[2 * qd + 1];
    const f2 cs0 = csp_t[2 * qd],     cs1 = csp_t[2 * qd + 1];
    const f2 ss0 = ssp_t[2 * qd],     ss1 = ssp_t[2 * qd + 1];

    const f2 num0 = fma2(Y2, ss0, X2 * cs0);
    const f2 num1 = fma2(Y2, ss1, X2 * cs1);
    const f2 L0 = fma2(nY2, cb0, fma2(X2, sb0, SID2));
    const f2 L1 = fma2(nY2, cb1, fma2(X2, sb1, SID2));
    const f2 rL0 = {__builtin_amdgcn_rcpf(L0.x), __builtin_amdgcn_rcpf(L0.y)};
    const f2 rL1 = {__builtin_amdgcn_rcpf(L1.x), __builtin_amdgcn_rcpf(L1.y)};
    const f2 tt0 = fma2(num0, rL0, C4075);   // t in [97.5, 717.5] -> no clamp
    const f2 tt1 = fma2(num1, rL1, C4075);
    const f2 m0 = SID2 * rL0, m1 = SID2 * rL1;
    const f2 w0 = m0 * m0, w1 = m1 * m1;
    const float iA = floorf(tt0.x), iB = floorf(tt0.y);
    const float iC = floorf(tt1.x), iD = floorf(tt1.y);
    const int i0A = (int)iA, i0B = (int)iB, i0C = (int)iC, i0D = (int)iD;
    const f2 fr0 = tt0 - (f2){iA, iB};
    const f2 fr1 = tt1 - (f2){iC, iD};
    const f2 a1p0 = w0 * fr0, a1p1 = w1 * fr1;
    const f2 a0p0 = w0 - a1p0, a0p1 = w1 - a1p1;
    const h2 wpA = pack_h2(a0p0.x, a1p0.x);
    const h2 wpB = pack_h2(a0p0.y, a1p0.y);
    const h2 wpC = pack_h2(a0p1.x, a1p1.x);
    const h2 wpD = pack_h2(a0p1.y, a1p1.y);

    // ---- 8 independent dwordx4 gathers ----
    const uint4* pA = (const uint4*)(pv + (i0A << 5));
    const uint4* pB = (const uint4*)(pv + VSTRIDE + (i0B << 5));
    const uint4* pC = (const uint4*)(pv + 2 * VSTRIDE + (i0C << 5));
    const uint4* pD = (const uint4*)(pv + 3 * VSTRIDE + (i0D << 5));
    const uint4 qA0 = pA[0], qA1 = pA[1];
    const uint4 qB0 = pB[0], qB1 = pB[1];
    const uint4 qC0 = pC[0], qC1 = pC[1];
    const uint4 qD0 = pD[0], qD1 = pD[1];

    acc[0] = dot2acc(wpA, qA0.x, acc[0]);
    acc[1] = dot2acc(wpA, qA0.y, acc[1]);
    acc[2] = dot2acc(wpA, qA0.z, acc[2]);
    acc[3] = dot2acc(wpA, qA0.w, acc[3]);
    acc[4] = dot2acc(wpA, qA1.x, acc[4]);
    acc[5] = dot2acc(wpA, qA1.y, acc[5]);
    acc[6] = dot2acc(wpA, qA1.z, acc[6]);
    acc[7] = dot2acc(wpA, qA1.w, acc[7]);

    acc[0] = dot2acc(wpB, qB0.x, acc[0]);
    acc[1] = dot2acc(wpB, qB0.y, acc[1]);
    acc[2] = dot2acc(wpB, qB0.z, acc[2]);
    acc[3] = dot2acc(wpB, qB0.w, acc[3]);
    acc[4] = dot2acc(wpB, qB1.x, acc[4]);
    acc[5] = dot2acc(wpB, qB1.y, acc[5]);
    acc[6] = dot2acc(wpB, qB1.z, acc[6]);
    acc[7] = dot2acc(wpB, qB1.w, acc[7]);

    acc[0] = dot2acc(wpC, qC0.x, acc[0]);
    acc[1] = dot2acc(wpC, qC0.y, acc[1]);
    acc[2] = dot2acc(wpC, qC0.z, acc[2]);
    acc[3] = dot2acc(wpC, qC0.w, acc[3]);
    acc[4] = dot2acc(wpC, qC1.x, acc[4]);
    acc[5] = dot2acc(wpC, qC1.y, acc[5]);
    acc[6] = dot2acc(wpC, qC1.z, acc[6]);
    acc[7] = dot2acc(wpC, qC1.w, acc[7]);

    acc[0] = dot2acc(wpD, qD0.x, acc[0]);
    acc[1] = dot2acc(wpD, qD0.y, acc[1]);
    acc[2] = dot2acc(wpD, qD0.z, acc[2]);
    acc[3] = dot2acc(wpD, qD0.w, acc[3]);
    acc[4] = dot2acc(wpD, qD1.x, acc[4]);
    acc[5] = dot2acc(wpD, qD1.y, acc[5]);
    acc[6] = dot2acc(wpD, qD1.z, acc[6]);
    acc[7] = dot2acc(wpD, qD1.w, acc[7]);

    pv += 4 * VSTRIDE;
  }

#pragma unroll
  for (int b = 0; b < NB; ++b)
    atomicAdd(&out[(b * IMGN + i) * IMGN + j], acc[b] * DBETA);
}

} // namespace

extern "C" void kernel_launch(void* const* d_in, const int* in_sizes, int n_in,
                              void* d_out, int out_size, void* d_ws, size_t ws_size,
                              hipStream_t stream) {
  const float* x = (const float*)d_in[0];
  const float* filt = (const float*)d_in[1];
  float* out = (float*)d_out;
  h2* sino2 = (h2*)d_ws;   // 720*816*8 paired-fp16 words = 18.8 MB

  (void)hipMemsetAsync(out, 0, (size_t)out_size * sizeof(float), stream);
  filt_kernel<<<NVIEW * 2, 256, 0, stream>>>(x, filt, sino2);
  bp_kernel<<<dim3(IMGN / 16, IMGN / 16, NSPLIT), 256, 0, stream>>>(sino2, out);
}